// Round 1
// baseline (29.520 us; speedup 1.0000x reference)
//
#include <hip/hip_runtime.h>

// Quanvolution: 4-wire RY/CNOT circuit per 2x2 patch, real amplitudes.
// State index: idx = i_w0*8 + i_w1*4 + i_w2*2 + i_w3  (wire w -> bit stride 8>>w)

__global__ void prep_trig_kernel(const float* __restrict__ params,
                                 float* __restrict__ trig) {
    int i = threadIdx.x;
    if (i < 8) {
        float th = 0.5f * params[i];
        trig[2 * i]     = cosf(th);
        trig[2 * i + 1] = sinf(th);
    }
}

template <int W>
__device__ __forceinline__ void apply_ry(float st[16], float c, float sn) {
    constexpr int S = 8 >> W;
#pragma unroll
    for (int i = 0; i < 16; ++i) {
        if ((i & S) == 0) {
            float a = st[i], b = st[i | S];
            st[i]     = c * a - sn * b;
            st[i | S] = sn * a + c * b;
        }
    }
}

template <int C, int T>
__device__ __forceinline__ void cnot(float st[16]) {
    constexpr int CS = 8 >> C, TS = 8 >> T;
#pragma unroll
    for (int i = 0; i < 16; ++i) {
        if ((i & CS) != 0 && (i & TS) == 0) {
            float t = st[i];
            st[i] = st[i | TS];
            st[i | TS] = t;
        }
    }
}

__global__ __launch_bounds__(256) void quanv_kernel(
    const float* __restrict__ x,     // (B,1,28,28)
    const float* __restrict__ trig,  // 16 floats: [cos,sin] per (layer,wire); may be null
    const float* __restrict__ params,// (2,4) raw angles (fallback path)
    float* __restrict__ out,         // (B, 784)
    int total)                       // B*196
{
    int i = blockIdx.x * 256 + threadIdx.x;
    if (i >= total) return;

    // variational-angle trig (wave-uniform)
    float pc[8], ps[8];
    if (trig) {
#pragma unroll
        for (int k = 0; k < 4; ++k) {
            float4 t = reinterpret_cast<const float4*>(trig)[k];
            pc[2 * k]     = t.x; ps[2 * k]     = t.y;
            pc[2 * k + 1] = t.z; ps[2 * k + 1] = t.w;
        }
    } else {
#pragma unroll
        for (int k = 0; k < 8; ++k) __sincosf(0.5f * params[k], &ps[k], &pc[k]);
    }

    int b = i / 196;
    int p = i - b * 196;
    int r = p / 14;
    int c = p - r * 14;

    const float* row = x + (size_t)b * 784 + r * 56 + c * 2;
    float2 top = *reinterpret_cast<const float2*>(row);
    float2 bot = *reinterpret_cast<const float2*>(row + 28);

    float xv[4] = {top.x, top.y, bot.x, bot.y};
    float cw[4], sw[4];
#pragma unroll
    for (int w = 0; w < 4; ++w) __sincosf(0.5f * xv[w], &sw[w], &cw[w]);

    // data encoding: product state after RY(x_w) on |0000>
    float st[16];
    {
        float r00 = cw[0] * cw[1], r01 = cw[0] * sw[1];
        float r10 = sw[0] * cw[1], r11 = sw[0] * sw[1];
        float q00 = cw[2] * cw[3], q01 = cw[2] * sw[3];
        float q10 = sw[2] * cw[3], q11 = sw[2] * sw[3];
        st[0]  = r00 * q00; st[1]  = r00 * q01; st[2]  = r00 * q10; st[3]  = r00 * q11;
        st[4]  = r01 * q00; st[5]  = r01 * q01; st[6]  = r01 * q10; st[7]  = r01 * q11;
        st[8]  = r10 * q00; st[9]  = r10 * q01; st[10] = r10 * q10; st[11] = r10 * q11;
        st[12] = r11 * q00; st[13] = r11 * q01; st[14] = r11 * q10; st[15] = r11 * q11;
    }

    cnot<0, 1>(st); cnot<1, 2>(st); cnot<2, 3>(st);

#pragma unroll
    for (int l = 0; l < 2; ++l) {
        apply_ry<0>(st, pc[l * 4 + 0], ps[l * 4 + 0]);
        apply_ry<1>(st, pc[l * 4 + 1], ps[l * 4 + 1]);
        apply_ry<2>(st, pc[l * 4 + 2], ps[l * 4 + 2]);
        apply_ry<3>(st, pc[l * 4 + 3], ps[l * 4 + 3]);
        cnot<0, 1>(st); cnot<1, 2>(st); cnot<2, 3>(st);
    }

    float pr[16];
#pragma unroll
    for (int k = 0; k < 16; ++k) pr[k] = st[k] * st[k];

    float z[4];
#pragma unroll
    for (int w = 0; w < 4; ++w) {
        const int S = 8 >> w;
        float zp = 0.f, zm = 0.f;
#pragma unroll
        for (int k = 0; k < 16; ++k) {
            if (k & S) zm += pr[k]; else zp += pr[k];
        }
        z[w] = zp - zm;
    }

    *reinterpret_cast<float4*>(out + (size_t)i * 4) =
        make_float4(z[0], z[1], z[2], z[3]);
}

extern "C" void kernel_launch(void* const* d_in, const int* in_sizes, int n_in,
                              void* d_out, int out_size, void* d_ws, size_t ws_size,
                              hipStream_t stream) {
    const float* x      = (const float*)d_in[0];
    const float* params = (const float*)d_in[1];
    float* out = (float*)d_out;

    int B = in_sizes[0] / 784;       // 8192
    int total = B * 196;             // patches

    float* trig = nullptr;
    if (d_ws && ws_size >= 16 * sizeof(float)) {
        trig = (float*)d_ws;
        prep_trig_kernel<<<1, 64, 0, stream>>>(params, trig);
    }

    int grid = (total + 255) / 256;
    quanv_kernel<<<grid, 256, 0, stream>>>(x, trig, params, out, total);
}

// Round 2
// 23.962 us; speedup vs baseline: 1.2319x; 1.2319x over previous
//
#include <hip/hip_runtime.h>

// Quanvolution: 4-wire RY/CNOT circuit per 2x2 patch, real amplitudes.
// State index: idx = i_w0*8 + i_w1*4 + i_w2*2 + i_w3  (wire w -> bit stride 8>>w)
// Each thread handles TWO horizontally-adjacent patches (one float4 per image row).

#define REV 0.07957747155f  // 1/(4*pi): theta -> (theta/2) in revolutions

__device__ __forceinline__ float fsin(float rev) {
    float o; asm("v_sin_f32 %0, %1" : "=v"(o) : "v"(rev)); return o;
}
__device__ __forceinline__ float fcos(float rev) {
    float o; asm("v_cos_f32 %0, %1" : "=v"(o) : "v"(rev)); return o;
}

template <int W>
__device__ __forceinline__ void apply_ry(float st[16], float c, float sn) {
    constexpr int S = 8 >> W;
#pragma unroll
    for (int i = 0; i < 16; ++i) {
        if ((i & S) == 0) {
            float a = st[i], b = st[i | S];
            st[i]     = c * a - sn * b;
            st[i | S] = sn * a + c * b;
        }
    }
}

template <int C, int T>
__device__ __forceinline__ void cnot(float st[16]) {
    constexpr int CS = 8 >> C, TS = 8 >> T;
#pragma unroll
    for (int i = 0; i < 16; ++i) {
        if ((i & CS) != 0 && (i & TS) == 0) {
            float t = st[i];
            st[i] = st[i | TS];
            st[i | TS] = t;
        }
    }
}

__device__ __forceinline__ void circuit(float x0, float x1, float x2, float x3,
                                        const float pc[8], const float ps[8],
                                        float4& z) {
    float cw[4], sw[4];
    float xv[4] = {x0, x1, x2, x3};
#pragma unroll
    for (int w = 0; w < 4; ++w) {
        float rev = xv[w] * REV;
        sw[w] = fsin(rev);
        cw[w] = fcos(rev);
    }

    // product state after data-encoding RYs on |0000>
    float st[16];
    {
        float r00 = cw[0] * cw[1], r01 = cw[0] * sw[1];
        float r10 = sw[0] * cw[1], r11 = sw[0] * sw[1];
        float q00 = cw[2] * cw[3], q01 = cw[2] * sw[3];
        float q10 = sw[2] * cw[3], q11 = sw[2] * sw[3];
        st[0]  = r00 * q00; st[1]  = r00 * q01; st[2]  = r00 * q10; st[3]  = r00 * q11;
        st[4]  = r01 * q00; st[5]  = r01 * q01; st[6]  = r01 * q10; st[7]  = r01 * q11;
        st[8]  = r10 * q00; st[9]  = r10 * q01; st[10] = r10 * q10; st[11] = r10 * q11;
        st[12] = r11 * q00; st[13] = r11 * q01; st[14] = r11 * q10; st[15] = r11 * q11;
    }

    cnot<0, 1>(st); cnot<1, 2>(st); cnot<2, 3>(st);

#pragma unroll
    for (int l = 0; l < 2; ++l) {
        apply_ry<0>(st, pc[l * 4 + 0], ps[l * 4 + 0]);
        apply_ry<1>(st, pc[l * 4 + 1], ps[l * 4 + 1]);
        apply_ry<2>(st, pc[l * 4 + 2], ps[l * 4 + 2]);
        apply_ry<3>(st, pc[l * 4 + 3], ps[l * 4 + 3]);
        cnot<0, 1>(st); cnot<1, 2>(st); cnot<2, 3>(st);
    }

    float pr[16];
#pragma unroll
    for (int k = 0; k < 16; ++k) pr[k] = st[k] * st[k];

    // q_j = pr[2j]+pr[2j+1]; shared subsum tree
    float q[8];
#pragma unroll
    for (int j = 0; j < 8; ++j) q[j] = pr[2 * j] + pr[2 * j + 1];
    float r0 = q[0] + q[1], r1 = q[2] + q[3], r2 = q[4] + q[5], r3 = q[6] + q[7];
    z.x = (r0 + r1) - (r2 + r3);                                  // wire 0 (stride 8)
    z.y = (r0 - r1) + (r2 - r3);                                  // wire 1 (stride 4)
    z.z = (q[0] - q[1]) + (q[2] - q[3]) + (q[4] - q[5]) + (q[6] - q[7]); // wire 2
    float d0 = pr[0] - pr[1], d1 = pr[2] - pr[3], d2 = pr[4] - pr[5], d3 = pr[6] - pr[7];
    float d4 = pr[8] - pr[9], d5 = pr[10] - pr[11], d6 = pr[12] - pr[13], d7 = pr[14] - pr[15];
    z.w = ((d0 + d1) + (d2 + d3)) + ((d4 + d5) + (d6 + d7));      // wire 3
}

__global__ __launch_bounds__(256) void quanv_kernel(
    const float* __restrict__ x,      // (B,1,28,28)
    const float* __restrict__ params, // (2,4) raw angles
    float* __restrict__ out,          // (B, 784)
    int totalPairs)                   // B*98  (patch pairs)
{
    int i = blockIdx.x * 256 + threadIdx.x;
    if (i >= totalPairs) return;

    // batch-invariant variational trig (uniform; params loads become s_load)
    float pc[8], ps[8];
#pragma unroll
    for (int k = 0; k < 8; ++k) {
        float rev = params[k] * REV;
        ps[k] = fsin(rev);
        pc[k] = fcos(rev);
    }

    int b  = i / 98;
    int q  = i - b * 98;
    int r  = q / 7;
    int cp = q - r * 7;   // pair index: cols 4*cp .. 4*cp+3

    const float* base = x + (size_t)b * 784 + r * 56 + cp * 4;
    float4 top = *reinterpret_cast<const float4*>(base);
    float4 bot = *reinterpret_cast<const float4*>(base + 28);

    float4 z0, z1;
    circuit(top.x, top.y, bot.x, bot.y, pc, ps, z0);
    circuit(top.z, top.w, bot.z, bot.w, pc, ps, z1);

    size_t outBase = ((size_t)b * 196 + r * 14 + cp * 2) * 4;
    reinterpret_cast<float4*>(out + outBase)[0] = z0;
    reinterpret_cast<float4*>(out + outBase)[1] = z1;
}

extern "C" void kernel_launch(void* const* d_in, const int* in_sizes, int n_in,
                              void* d_out, int out_size, void* d_ws, size_t ws_size,
                              hipStream_t stream) {
    const float* x      = (const float*)d_in[0];
    const float* params = (const float*)d_in[1];
    float* out = (float*)d_out;

    int B = in_sizes[0] / 784;   // 8192
    int totalPairs = B * 98;     // 802816

    int grid = (totalPairs + 255) / 256;
    quanv_kernel<<<grid, 256, 0, stream>>>(x, params, out, totalPairs);
}

// Round 3
// 22.642 us; speedup vs baseline: 1.3038x; 1.0583x over previous
//
#include <hip/hip_runtime.h>

// Quanvolution: 4-wire RY/CNOT circuit per 2x2 patch, real amplitudes.
// State index: idx = i_w0*8 + i_w1*4 + i_w2*2 + i_w3  (wire w -> bit stride 8>>w)
// Each thread handles TWO horizontally-adjacent patches (one float4 per image row).
// Variational RYs applied in tan-form (2 fma/butterfly); global scale removed by
// normalizing with the total probability at measurement (state is unit-norm).

#define REV 0.07957747155f  // 1/(4*pi): theta -> (theta/2) in revolutions

__device__ __forceinline__ float fsin(float rev) {
    float o; asm("v_sin_f32 %0, %1" : "=v"(o) : "v"(rev)); return o;
}
__device__ __forceinline__ float fcos(float rev) {
    float o; asm("v_cos_f32 %0, %1" : "=v"(o) : "v"(rev)); return o;
}

__global__ void prep_tan_kernel(const float* __restrict__ params,
                                float* __restrict__ t) {
    int i = threadIdx.x;
    if (i < 8) t[i] = tanf(0.5f * params[i]);
}

// RY in tan-form: [[1,-t],[t,1]] (scale cos(theta/2) deferred to normalization)
template <int W>
__device__ __forceinline__ void apply_ry_t(float st[16], float t) {
    constexpr int S = 8 >> W;
#pragma unroll
    for (int i = 0; i < 16; ++i) {
        if ((i & S) == 0) {
            float a = st[i], b = st[i | S];
            st[i]     = fmaf(-t, b, a);
            st[i | S] = fmaf(t, a, b);
        }
    }
}

template <int C, int T>
__device__ __forceinline__ void cnot(float st[16]) {
    constexpr int CS = 8 >> C, TS = 8 >> T;
#pragma unroll
    for (int i = 0; i < 16; ++i) {
        if ((i & CS) != 0 && (i & TS) == 0) {
            float t = st[i];
            st[i] = st[i | TS];
            st[i | TS] = t;
        }
    }
}

__device__ __forceinline__ void circuit(float x0, float x1, float x2, float x3,
                                        const float tv[8], float4& z) {
    float cw[4], sw[4];
    float xv[4] = {x0, x1, x2, x3};
#pragma unroll
    for (int w = 0; w < 4; ++w) {
        float rev = xv[w] * REV;
        sw[w] = fsin(rev);
        cw[w] = fcos(rev);
    }

    // product state after data-encoding RYs on |0000>
    float st[16];
    {
        float r00 = cw[0] * cw[1], r01 = cw[0] * sw[1];
        float r10 = sw[0] * cw[1], r11 = sw[0] * sw[1];
        float q00 = cw[2] * cw[3], q01 = cw[2] * sw[3];
        float q10 = sw[2] * cw[3], q11 = sw[2] * sw[3];
        st[0]  = r00 * q00; st[1]  = r00 * q01; st[2]  = r00 * q10; st[3]  = r00 * q11;
        st[4]  = r01 * q00; st[5]  = r01 * q01; st[6]  = r01 * q10; st[7]  = r01 * q11;
        st[8]  = r10 * q00; st[9]  = r10 * q01; st[10] = r10 * q10; st[11] = r10 * q11;
        st[12] = r11 * q00; st[13] = r11 * q01; st[14] = r11 * q10; st[15] = r11 * q11;
    }

    cnot<0, 1>(st); cnot<1, 2>(st); cnot<2, 3>(st);

#pragma unroll
    for (int l = 0; l < 2; ++l) {
        apply_ry_t<0>(st, tv[l * 4 + 0]);
        apply_ry_t<1>(st, tv[l * 4 + 1]);
        apply_ry_t<2>(st, tv[l * 4 + 2]);
        apply_ry_t<3>(st, tv[l * 4 + 3]);
        cnot<0, 1>(st); cnot<1, 2>(st); cnot<2, 3>(st);
    }

    float pr[16];
#pragma unroll
    for (int k = 0; k < 16; ++k) pr[k] = st[k] * st[k];

    // single-bit parity sums with shared subsums; normalize by total
    float a[8], d[8];
#pragma unroll
    for (int j = 0; j < 8; ++j) {
        a[j] = pr[2 * j] + pr[2 * j + 1];
        d[j] = pr[2 * j] - pr[2 * j + 1];
    }
    float z3 = ((d[0] + d[1]) + (d[2] + d[3])) + ((d[4] + d[5]) + (d[6] + d[7]));
    float b0 = a[0] + a[1], b1 = a[2] + a[3], b2 = a[4] + a[5], b3 = a[6] + a[7];
    float e0 = a[0] - a[1], e1 = a[2] - a[3], e2 = a[4] - a[5], e3 = a[6] - a[7];
    float z2 = (e0 + e1) + (e2 + e3);
    float z1 = (b0 - b1) + (b2 - b3);
    float c0 = b0 + b1, c1 = b2 + b3;
    float z0 = c0 - c1;
    float tot = c0 + c1;
    float inv = __builtin_amdgcn_rcpf(tot);
    z.x = z0 * inv; z.y = z1 * inv; z.z = z2 * inv; z.w = z3 * inv;
}

__global__ __launch_bounds__(256) void quanv_kernel(
    const float* __restrict__ x,      // (B,1,28,28)
    const float* __restrict__ tan8,   // 8 floats: tan(param/2), or null
    const float* __restrict__ params, // (2,4) raw angles (fallback)
    float* __restrict__ out,          // (B, 784)
    int totalPairs)                   // B*98  (patch pairs)
{
    int i = blockIdx.x * 256 + threadIdx.x;
    if (i >= totalPairs) return;

    float tv[8];
    if (tan8) {
        float4 t01 = reinterpret_cast<const float4*>(tan8)[0];
        float4 t23 = reinterpret_cast<const float4*>(tan8)[1];
        tv[0] = t01.x; tv[1] = t01.y; tv[2] = t01.z; tv[3] = t01.w;
        tv[4] = t23.x; tv[5] = t23.y; tv[6] = t23.z; tv[7] = t23.w;
    } else {
#pragma unroll
        for (int k = 0; k < 8; ++k) {
            float rev = params[k] * REV;
            tv[k] = fsin(rev) * __builtin_amdgcn_rcpf(fcos(rev));
        }
    }

    int b  = i / 98;
    int q  = i - b * 98;
    int r  = q / 7;
    int cp = q - r * 7;   // pair index: cols 4*cp .. 4*cp+3

    const float* base = x + (size_t)b * 784 + r * 56 + cp * 4;
    float4 top = *reinterpret_cast<const float4*>(base);
    float4 bot = *reinterpret_cast<const float4*>(base + 28);

    float4 z0, z1;
    circuit(top.x, top.y, bot.x, bot.y, tv, z0);
    circuit(top.z, top.w, bot.z, bot.w, tv, z1);

    size_t outBase = ((size_t)b * 196 + r * 14 + cp * 2) * 4;
    reinterpret_cast<float4*>(out + outBase)[0] = z0;
    reinterpret_cast<float4*>(out + outBase)[1] = z1;
}

extern "C" void kernel_launch(void* const* d_in, const int* in_sizes, int n_in,
                              void* d_out, int out_size, void* d_ws, size_t ws_size,
                              hipStream_t stream) {
    const float* x      = (const float*)d_in[0];
    const float* params = (const float*)d_in[1];
    float* out = (float*)d_out;

    int B = in_sizes[0] / 784;   // 8192
    int totalPairs = B * 98;     // 802816

    float* tan8 = nullptr;
    if (d_ws && ws_size >= 8 * sizeof(float)) {
        tan8 = (float*)d_ws;
        prep_tan_kernel<<<1, 64, 0, stream>>>(params, tan8);
    }

    int grid = (totalPairs + 255) / 256;
    quanv_kernel<<<grid, 256, 0, stream>>>(x, tan8, params, out, totalPairs);
}

// Round 4
// 17.093 us; speedup vs baseline: 1.7270x; 1.3246x over previous
//
#include <hip/hip_runtime.h>

// Quanvolution: 4-wire RY/CNOT circuit per 2x2 patch, real amplitudes.
// State index: idx = i_w0*8 + i_w1*4 + i_w2*2 + i_w3  (wire w -> bit stride 8>>w)
// Each thread handles TWO horizontally-adjacent patches; the two independent
// circuits ride the lo/hi halves of packed-fp32 (v_pk_*_f32) vectors.
// Variational RYs in tan form (2 pk_fma/butterfly); global scale removed by
// normalizing with total probability at measurement.

typedef float f32x2 __attribute__((ext_vector_type(2)));

#define REV 0.07957747155f  // 1/(4*pi): theta -> (theta/2) in revolutions

__device__ __forceinline__ float fsin(float rev) {
    float o; asm("v_sin_f32 %0, %1" : "=v"(o) : "v"(rev)); return o;
}
__device__ __forceinline__ float fcos(float rev) {
    float o; asm("v_cos_f32 %0, %1" : "=v"(o) : "v"(rev)); return o;
}
__device__ __forceinline__ f32x2 pk_fma(f32x2 a, f32x2 b, f32x2 c) {
    return __builtin_elementwise_fma(a, b, c);
}

// RY in tan-form: [[1,-t],[t,1]] (cos scale deferred to normalization)
template <int W>
__device__ __forceinline__ void apply_ry_t(f32x2 st[16], f32x2 tb) {
    constexpr int S = 8 >> W;
#pragma unroll
    for (int i = 0; i < 16; ++i) {
        if ((i & S) == 0) {
            f32x2 a = st[i], b = st[i | S];
            st[i]     = pk_fma(-tb, b, a);
            st[i | S] = pk_fma(tb, a, b);
        }
    }
}

template <int C, int T>
__device__ __forceinline__ void cnot(f32x2 st[16]) {
    constexpr int CS = 8 >> C, TS = 8 >> T;
#pragma unroll
    for (int i = 0; i < 16; ++i) {
        if ((i & CS) != 0 && (i & TS) == 0) {
            f32x2 t = st[i];
            st[i] = st[i | TS];
            st[i | TS] = t;
        }
    }
}

__global__ __launch_bounds__(256) void quanv_kernel(
    const float* __restrict__ x,      // (B,1,28,28)
    const float* __restrict__ params, // (2,4) raw angles
    float* __restrict__ out,          // (B, 784)
    int totalPairs)                   // B*98 (patch pairs)
{
    int i = blockIdx.x * 256 + threadIdx.x;
    if (i >= totalPairs) return;

    // batch-invariant variational tans (uniform; params -> s_loads)
    f32x2 tv[8];
#pragma unroll
    for (int k = 0; k < 8; ++k) {
        float rev = params[k] * REV;
        float t = fsin(rev) * __builtin_amdgcn_rcpf(fcos(rev));
        tv[k] = (f32x2){t, t};
    }

    int b  = i / 98;
    int q  = i - b * 98;
    int r  = q / 7;
    int cp = q - r * 7;   // pair index: cols 4*cp .. 4*cp+3

    const float* base = x + (size_t)b * 784 + r * 56 + cp * 4;
    float4 top = *reinterpret_cast<const float4*>(base);
    float4 bot = *reinterpret_cast<const float4*>(base + 28);

    // lo half = circuit 0 (cols 2cp*2), hi half = circuit 1
    float xs0[4] = {top.x, top.y, bot.x, bot.y};
    float xs1[4] = {top.z, top.w, bot.z, bot.w};
    f32x2 cw[4], sw[4];
#pragma unroll
    for (int w = 0; w < 4; ++w) {
        float r0 = xs0[w] * REV, r1 = xs1[w] * REV;
        sw[w] = (f32x2){fsin(r0), fsin(r1)};
        cw[w] = (f32x2){fcos(r0), fcos(r1)};
    }

    // product state after data-encoding RYs on |0000>
    f32x2 st[16];
    {
        f32x2 r00 = cw[0] * cw[1], r01 = cw[0] * sw[1];
        f32x2 r10 = sw[0] * cw[1], r11 = sw[0] * sw[1];
        f32x2 q00 = cw[2] * cw[3], q01 = cw[2] * sw[3];
        f32x2 q10 = sw[2] * cw[3], q11 = sw[2] * sw[3];
        st[0]  = r00 * q00; st[1]  = r00 * q01; st[2]  = r00 * q10; st[3]  = r00 * q11;
        st[4]  = r01 * q00; st[5]  = r01 * q01; st[6]  = r01 * q10; st[7]  = r01 * q11;
        st[8]  = r10 * q00; st[9]  = r10 * q01; st[10] = r10 * q10; st[11] = r10 * q11;
        st[12] = r11 * q00; st[13] = r11 * q01; st[14] = r11 * q10; st[15] = r11 * q11;
    }

    cnot<0, 1>(st); cnot<1, 2>(st); cnot<2, 3>(st);

#pragma unroll
    for (int l = 0; l < 2; ++l) {
        apply_ry_t<0>(st, tv[l * 4 + 0]);
        apply_ry_t<1>(st, tv[l * 4 + 1]);
        apply_ry_t<2>(st, tv[l * 4 + 2]);
        apply_ry_t<3>(st, tv[l * 4 + 3]);
        cnot<0, 1>(st); cnot<1, 2>(st); cnot<2, 3>(st);
    }

    f32x2 pr[16];
#pragma unroll
    for (int k = 0; k < 16; ++k) pr[k] = st[k] * st[k];

    // single-bit parity sums with shared subsums; normalize by total
    f32x2 a[8], d[8];
#pragma unroll
    for (int j = 0; j < 8; ++j) {
        a[j] = pr[2 * j] + pr[2 * j + 1];
        d[j] = pr[2 * j] - pr[2 * j + 1];
    }
    f32x2 z3 = ((d[0] + d[1]) + (d[2] + d[3])) + ((d[4] + d[5]) + (d[6] + d[7]));
    f32x2 b0 = a[0] + a[1], b1 = a[2] + a[3], b2 = a[4] + a[5], b3 = a[6] + a[7];
    f32x2 e0 = a[0] - a[1], e1 = a[2] - a[3], e2 = a[4] - a[5], e3 = a[6] - a[7];
    f32x2 z2 = (e0 + e1) + (e2 + e3);
    f32x2 z1 = (b0 - b1) + (b2 - b3);
    f32x2 c0 = b0 + b1, c1 = b2 + b3;
    f32x2 z0 = c0 - c1;
    f32x2 tot = c0 + c1;
    f32x2 inv = (f32x2){__builtin_amdgcn_rcpf(tot.x), __builtin_amdgcn_rcpf(tot.y)};
    z0 *= inv; z1 *= inv; z2 *= inv; z3 *= inv;

    size_t outBase = ((size_t)b * 196 + r * 14 + cp * 2) * 4;
    reinterpret_cast<float4*>(out + outBase)[0] = make_float4(z0.x, z1.x, z2.x, z3.x);
    reinterpret_cast<float4*>(out + outBase)[1] = make_float4(z0.y, z1.y, z2.y, z3.y);
}

extern "C" void kernel_launch(void* const* d_in, const int* in_sizes, int n_in,
                              void* d_out, int out_size, void* d_ws, size_t ws_size,
                              hipStream_t stream) {
    const float* x      = (const float*)d_in[0];
    const float* params = (const float*)d_in[1];
    float* out = (float*)d_out;

    int B = in_sizes[0] / 784;   // 8192
    int totalPairs = B * 98;     // 802816

    int grid = (totalPairs + 255) / 256;
    quanv_kernel<<<grid, 256, 0, stream>>>(x, params, out, totalPairs);
}

// Round 5
// 16.787 us; speedup vs baseline: 1.7585x; 1.0182x over previous
//
#include <hip/hip_runtime.h>

// Quanvolution: 4-wire RY/CNOT circuit per 2x2 patch, real amplitudes.
// State index: idx = i_w0*8 + i_w1*4 + i_w2*2 + i_w3  (wire w -> bit stride 8>>w)
// Two patches per thread ride lo/hi halves of packed-fp32 (v_pk_*_f32).
// Variational RYs in tan form (2 pk_fma/butterfly), tans computed once per
// block (lanes 0-7) -> LDS -> readfirstlane -> SGPRs. Data-encoding sincos via
// packed polynomial (arg in [0,0.5)). Global scale removed by normalization.

typedef float f32x2 __attribute__((ext_vector_type(2)));

__device__ __forceinline__ f32x2 pk_fma(f32x2 a, f32x2 b, f32x2 c) {
    return __builtin_elementwise_fma(a, b, c);
}
__device__ __forceinline__ f32x2 splat(float v) { return (f32x2){v, v}; }
__device__ __forceinline__ float uniformf(float v) {
    return __int_as_float(__builtin_amdgcn_readfirstlane(__float_as_int(v)));
}

// s = sin(x/2), c = cos(x/2) for x in [0,1): Taylor deg 7/8, err < 2e-6
__device__ __forceinline__ void pk_sincos_half(f32x2 x, f32x2& s, f32x2& c) {
    f32x2 t = x * 0.5f;
    f32x2 u = t * t;
    f32x2 ps = pk_fma(u, splat(8.3333333e-3f), splat(-0.16666667f));
    ps = pk_fma(u, ps, splat(1.0f));
    s = t * ps;
    f32x2 pc = pk_fma(u, splat(-1.3888889e-3f), splat(4.1666667e-2f));
    pc = pk_fma(u, pc, splat(-0.5f));
    c = pk_fma(u, pc, splat(1.0f));
}

// RY in tan-form: [[1,-t],[t,1]] (cos scale deferred to normalization)
template <int W>
__device__ __forceinline__ void apply_ry_t(f32x2 st[16], f32x2 tb, f32x2 ntb) {
    constexpr int S = 8 >> W;
#pragma unroll
    for (int i = 0; i < 16; ++i) {
        if ((i & S) == 0) {
            f32x2 a = st[i], b = st[i | S];
            st[i]     = pk_fma(ntb, b, a);
            st[i | S] = pk_fma(tb, a, b);
        }
    }
}

template <int C, int T>
__device__ __forceinline__ void cnot(f32x2 st[16]) {
    constexpr int CS = 8 >> C, TS = 8 >> T;
#pragma unroll
    for (int i = 0; i < 16; ++i) {
        if ((i & CS) != 0 && (i & TS) == 0) {
            f32x2 t = st[i];
            st[i] = st[i | TS];
            st[i | TS] = t;
        }
    }
}

__global__ __launch_bounds__(256, 4) void quanv_kernel(
    const float* __restrict__ x,      // (B,1,28,28)
    const float* __restrict__ params, // (2,4) raw angles
    float* __restrict__ out,          // (B, 784)
    int totalPairs)                   // B*98 (patch pairs)
{
    __shared__ float tl[8];
    int tid = threadIdx.x;
    if (tid < 8) tl[tid] = tanf(0.5f * params[tid]);

    int i = blockIdx.x * 256 + tid;
    int b  = i / 98;
    int q  = i - b * 98;
    int r  = q / 7;
    int cp = q - r * 7;   // pair index: cols 4*cp .. 4*cp+3
    bool valid = (i < totalPairs);

    // issue global loads before the barrier so HBM latency hides
    const float* base = x + (size_t)b * 784 + r * 56 + cp * 4;
    float4 top = make_float4(0.f, 0.f, 0.f, 0.f), bot = top;
    if (valid) {
        top = *reinterpret_cast<const float4*>(base);
        bot = *reinterpret_cast<const float4*>(base + 28);
    }

    __syncthreads();
    // wave-uniform tans -> SGPRs
    float t0 = uniformf(tl[0]), t1 = uniformf(tl[1]);
    float t2 = uniformf(tl[2]), t3 = uniformf(tl[3]);
    float t4 = uniformf(tl[4]), t5 = uniformf(tl[5]);
    float t6 = uniformf(tl[6]), t7 = uniformf(tl[7]);
    if (!valid) return;

    // lo half = circuit 0, hi half = circuit 1
    f32x2 cw[4], sw[4];
    pk_sincos_half((f32x2){top.x, top.z}, sw[0], cw[0]);
    pk_sincos_half((f32x2){top.y, top.w}, sw[1], cw[1]);
    pk_sincos_half((f32x2){bot.x, bot.z}, sw[2], cw[2]);
    pk_sincos_half((f32x2){bot.y, bot.w}, sw[3], cw[3]);

    // product state after data-encoding RYs on |0000>
    f32x2 st[16];
    {
        f32x2 r00 = cw[0] * cw[1], r01 = cw[0] * sw[1];
        f32x2 r10 = sw[0] * cw[1], r11 = sw[0] * sw[1];
        f32x2 q00 = cw[2] * cw[3], q01 = cw[2] * sw[3];
        f32x2 q10 = sw[2] * cw[3], q11 = sw[2] * sw[3];
        st[0]  = r00 * q00; st[1]  = r00 * q01; st[2]  = r00 * q10; st[3]  = r00 * q11;
        st[4]  = r01 * q00; st[5]  = r01 * q01; st[6]  = r01 * q10; st[7]  = r01 * q11;
        st[8]  = r10 * q00; st[9]  = r10 * q01; st[10] = r10 * q10; st[11] = r10 * q11;
        st[12] = r11 * q00; st[13] = r11 * q01; st[14] = r11 * q10; st[15] = r11 * q11;
    }

    cnot<0, 1>(st); cnot<1, 2>(st); cnot<2, 3>(st);

    apply_ry_t<0>(st, splat(t0), splat(-t0));
    apply_ry_t<1>(st, splat(t1), splat(-t1));
    apply_ry_t<2>(st, splat(t2), splat(-t2));
    apply_ry_t<3>(st, splat(t3), splat(-t3));
    cnot<0, 1>(st); cnot<1, 2>(st); cnot<2, 3>(st);
    apply_ry_t<0>(st, splat(t4), splat(-t4));
    apply_ry_t<1>(st, splat(t5), splat(-t5));
    apply_ry_t<2>(st, splat(t6), splat(-t6));
    apply_ry_t<3>(st, splat(t7), splat(-t7));
    cnot<0, 1>(st); cnot<1, 2>(st); cnot<2, 3>(st);

    // squares in place
#pragma unroll
    for (int k = 0; k < 16; ++k) st[k] = st[k] * st[k];

    // single-bit parity sums with shared subsums; normalize by total
    f32x2 a0 = st[0] + st[1],   d0 = st[0] - st[1];
    f32x2 a1 = st[2] + st[3],   d1 = st[2] - st[3];
    f32x2 a2 = st[4] + st[5],   d2 = st[4] - st[5];
    f32x2 a3 = st[6] + st[7],   d3 = st[6] - st[7];
    f32x2 a4 = st[8] + st[9],   d4 = st[8] - st[9];
    f32x2 a5 = st[10] + st[11], d5 = st[10] - st[11];
    f32x2 a6 = st[12] + st[13], d6 = st[12] - st[13];
    f32x2 a7 = st[14] + st[15], d7 = st[14] - st[15];
    f32x2 z3 = ((d0 + d1) + (d2 + d3)) + ((d4 + d5) + (d6 + d7));
    f32x2 b0 = a0 + a1, b1 = a2 + a3, b2 = a4 + a5, b3 = a6 + a7;
    f32x2 z2 = (a0 - a1) + (a2 - a3) + (a4 - a5) + (a6 - a7);
    f32x2 z1 = (b0 - b1) + (b2 - b3);
    f32x2 c0 = b0 + b1, c1 = b2 + b3;
    f32x2 z0 = c0 - c1;
    f32x2 tot = c0 + c1;
    f32x2 inv = (f32x2){__builtin_amdgcn_rcpf(tot.x), __builtin_amdgcn_rcpf(tot.y)};
    z0 *= inv; z1 *= inv; z2 *= inv; z3 *= inv;

    size_t outBase = ((size_t)b * 196 + r * 14 + cp * 2) * 4;
    reinterpret_cast<float4*>(out + outBase)[0] = make_float4(z0.x, z1.x, z2.x, z3.x);
    reinterpret_cast<float4*>(out + outBase)[1] = make_float4(z0.y, z1.y, z2.y, z3.y);
}

extern "C" void kernel_launch(void* const* d_in, const int* in_sizes, int n_in,
                              void* d_out, int out_size, void* d_ws, size_t ws_size,
                              hipStream_t stream) {
    const float* x      = (const float*)d_in[0];
    const float* params = (const float*)d_in[1];
    float* out = (float*)d_out;

    int B = in_sizes[0] / 784;   // 8192
    int totalPairs = B * 98;     // 802816

    int grid = (totalPairs + 255) / 256;
    quanv_kernel<<<grid, 256, 0, stream>>>(x, params, out, totalPairs);
}